// Round 10
// baseline (884.854 us; speedup 1.0000x reference)
//
#include <hip/hip_runtime.h>
#include <hip/hip_fp16.h>

typedef unsigned short u16;
typedef unsigned int   u32;
typedef __attribute__((ext_vector_type(8))) _Float16 f16x8;
typedef __attribute__((ext_vector_type(4))) float    f32x4;

#define MFMA(a,b,c) __builtin_amdgcn_mfma_f32_16x16x32_f16(a,b,c,0,0,0)

__device__ __forceinline__ u16 f2h(float f) { return __half_as_ushort(__float2half(f)); }

__device__ __forceinline__ void load_lds16(const void* g, void* l) {
    __builtin_amdgcn_global_load_lds(
        (__attribute__((address_space(1))) void*)g,
        (__attribute__((address_space(3))) void*)l,
        16, 0, 0);
}

// ---------------------------------------------------------------- converts
__global__ __launch_bounds__(256) void k_conv_x(const float* __restrict__ in, u16* __restrict__ out)
{
    int i = blockIdx.x * 256 + threadIdx.x;              // n4 = 3145728 exactly
    float4 v = ((const float4*)in)[i];
    ushort4 o; o.x = f2h(v.x); o.y = f2h(v.y); o.z = f2h(v.z); o.w = f2h(v.w);
    ((ushort4*)out)[i] = o;
}

__global__ __launch_bounds__(256) void k_conv_w(const float* __restrict__ w0, const float* __restrict__ w1,
                                                const float* __restrict__ w2, u16* __restrict__ out)
{
    const float* src = (blockIdx.y == 0) ? w0 : (blockIdx.y == 1) ? w1 : w2;
    int i = blockIdx.x * 256 + threadIdx.x;              // per-matrix n4 = 147456 exactly
    float4 v = ((const float4*)src)[i];
    ushort4 o; o.x = f2h(v.x); o.y = f2h(v.y); o.z = f2h(v.z); o.w = f2h(v.w);
    ((ushort4*)(out + (size_t)blockIdx.y * 589824))[i] = o;
}

// ---------------------------------------------------------------- QKV GEMM (C[m,n] = sum_k A[m,k]*B[n,k])
// z=0: A=x(16384x768) B=Wq -> Q[s][e]; z=1: -> K[s][e]; z=2: A=Wv(768x768) B=x -> Vt[e][s] (pre-transposed V)
__global__ __launch_bounds__(256) void k_gemm(const u16* __restrict__ xb, const u16* __restrict__ Wb,
                                              u16* __restrict__ Qw, u16* __restrict__ Kw, u16* __restrict__ Vt)
{
    __shared__ u16 As[2][128*32];
    __shared__ u16 Bs[2][128*32];
    const int tid = threadIdx.x;
    const int l = tid & 63;
    const int wr = tid >> 7, wc = (tid >> 6) & 1;        // 4 waves -> 2x2 of 64x64
    const int z = blockIdx.z, bx = blockIdx.x;
    const u16 *Ap, *Bp; u16* Cp; int m0, n0; size_t ldc;
    if (z < 2) { Ap = xb; Bp = Wb + (size_t)z*589824; Cp = (z==0)?Qw:Kw; m0=(bx/6)*128; n0=(bx%6)*128; ldc=768; }
    else       { Ap = Wb + 2*589824; Bp = xb; Cp = Vt; m0=(bx%6)*128; n0=(bx/6)*128; ldc=16384; }

    f32x4 acc[4][4];
    #pragma unroll
    for (int i=0;i<4;++i)
        #pragma unroll
        for (int j=0;j<4;++j) acc[i][j] = (f32x4){0.f,0.f,0.f,0.f};

    const int srow = tid >> 2, sg = tid & 3;
    const int wb = (tid >> 6) << 10;

    #pragma unroll
    for (int i = 0; i < 2; ++i) {                        // stage kt=0
        load_lds16(Ap + (size_t)(m0 + i*64 + srow)*768 + sg*8, (char*)&As[0][0] + i*4096 + wb);
        load_lds16(Bp + (size_t)(n0 + i*64 + srow)*768 + sg*8, (char*)&Bs[0][0] + i*4096 + wb);
    }
    __syncthreads();
    int cur = 0;
    for (int kt = 0; kt < 24; ++kt) {
        if (kt + 1 < 24) {
            const int k0 = (kt+1)*32;
            #pragma unroll
            for (int i = 0; i < 2; ++i) {
                load_lds16(Ap + (size_t)(m0 + i*64 + srow)*768 + k0 + sg*8, (char*)&As[cur^1][0] + i*4096 + wb);
                load_lds16(Bp + (size_t)(n0 + i*64 + srow)*768 + k0 + sg*8, (char*)&Bs[cur^1][0] + i*4096 + wb);
            }
        }
        f16x8 a[4], b[4];
        #pragma unroll
        for (int mi = 0; mi < 4; ++mi) a[mi] = *(const f16x8*)&As[cur][(wr*64 + mi*16 + (l&15))*32 + (l>>4)*8];
        #pragma unroll
        for (int ni = 0; ni < 4; ++ni) b[ni] = *(const f16x8*)&Bs[cur][(wc*64 + ni*16 + (l&15))*32 + (l>>4)*8];
        #pragma unroll
        for (int mi = 0; mi < 4; ++mi)
            #pragma unroll
            for (int ni = 0; ni < 4; ++ni)
                acc[mi][ni] = MFMA(a[mi], b[ni], acc[mi][ni]);
        __syncthreads();
        cur ^= 1;
    }
    const int col = l & 15, rg = (l >> 4) * 4;
    #pragma unroll
    for (int mi = 0; mi < 4; ++mi)
        #pragma unroll
        for (int ni = 0; ni < 4; ++ni)
            #pragma unroll
            for (int j = 0; j < 4; ++j)
                Cp[(size_t)(m0 + wr*64 + mi*16 + rg + j) * ldc + n0 + wc*64 + ni*16 + col] = f2h(acc[mi][ni][j]);
}

// ---------------------------------------------------------------- flash attention v10
// 512 threads / 8 waves, QBLK=16, KVBLK=64. Grid 1024 = 4 batches x 256
// q-blocks, longest-first interleaved (v9 scheme, proven balance).
// NO K LDS staging: roles (jk4,kh2) give each K byte to exactly ONE wave, so
// LDS staging had zero cross-wave reuse -- it only cost 96KB LDS (1 block/CU,
// 2 waves/SIMD) and a vmcnt-drain at every barrier. QK now reads K fragments
// directly from global (L2/LLC-resident), like PV already does for V.
// LDS drops to ~11KB -> 2 blocks/CU (VGPR-bound), independent blocks overlap.
// Q in registers (qf[12]=48 VGPR); kh partials plain-stored to 2 f32 Sp
// planes (deterministic); Ps f16 144B rows; lagged PV.
#define SM_SCALE 0.03608439182435161f

__global__ __launch_bounds__(512) void k_flash(const u16* __restrict__ Qg, const u16* __restrict__ Kg,
                                               const u16* __restrict__ Vtg, float* __restrict__ Og)
{
    __shared__ float Sp[2][16][66];     // 8448 B, two f32 K-depth-partial planes
    __shared__ u16 Ps[16][72];          // 2304 B, f16 P, 144B rows (16B-aligned frags)
    __shared__ float row_m[16], row_l[16], row_sc[16];   // 192 B
    // total ~11 KB -> occupancy VGPR-bound (2 blocks/CU at <=128 VGPR)

    const int tid = threadIdx.x;
    const int w = tid >> 6, l = tid & 63;
    const int l15 = l & 15, l4 = l >> 4;
    const int jk = w & 3, kh = w >> 2;                   // QK role: k-cols jk*16, K-depth kh*384
    const int dg = w;                                    // PV role: 96 e-cols per wave
    const int b = blockIdx.x;
    const int batch = b & 3, qi16 = 255 - (b >> 2);      // longest blocks first
    const int q0 = qi16 * 16;
    const int NT = (qi16 >> 2) + 1;                      // 64-wide KV tiles
    const size_t bofs = (size_t)batch * 4096;
    const float NEG_INF = -__builtin_inff();

    if (tid < 16) { row_m[tid] = NEG_INF; row_l[tid] = 0.f; }

    // ---- Q tile -> registers (once): rows q0+l15, depth kh*384 + ks*32 + l4*8
    f16x8 qf[12];
    {
        const u16* qb = Qg + (bofs + q0 + l15)*768 + kh*384 + l4*8;
        #pragma unroll
        for (int ks = 0; ks < 12; ++ks)
            qf[ks] = *(const f16x8*)(qb + ks*32);
    }

    f32x4 oacc[6];
    #pragma unroll
    for (int i = 0; i < 6; ++i) oacc[i] = (f32x4){0.f,0.f,0.f,0.f};

    for (int t = 0; t < NT; ++t) {
        __syncthreads();                                 // A: Ps(t-1)/row_sc ready; Sp free
        // ---- QK(t): K fragments direct from global (rows jk*16+l15 of tile t)
        {
            const u16* kb = Kg + (bofs + (size_t)t*64 + jk*16 + l15)*768 + kh*384 + l4*8;
            f32x4 s0 = (f32x4){0.f,0.f,0.f,0.f}, s1 = (f32x4){0.f,0.f,0.f,0.f};
            #pragma unroll
            for (int h = 0; h < 2; ++h) {                // 2 groups of 6 frags (caps VGPR transients)
                f16x8 kf[6];
                #pragma unroll
                for (int ks = 0; ks < 6; ++ks)
                    kf[ks] = *(const f16x8*)(kb + (h*6 + ks)*32);
                #pragma unroll
                for (int ks = 0; ks < 6; ks += 2) {
                    s0 = MFMA(qf[h*6+ks],   kf[ks],   s0);
                    s1 = MFMA(qf[h*6+ks+1], kf[ks+1], s1);
                }
            }
            const int scc = jk*16 + l15, sr = l4*4;
            #pragma unroll
            for (int j = 0; j < 4; ++j)
                Sp[kh][sr + j][scc] = s0[j] + s1[j];     // plain store: deterministic
        }
        // ---- PV(t-1), lagged; Ps + V-from-global (transient regs)
        if (t > 0) {
            const int rb = l4*4;
            const float fr0 = row_sc[rb], fr1 = row_sc[rb+1], fr2 = row_sc[rb+2], fr3 = row_sc[rb+3];
            f16x8 pa0 = *(const f16x8*)((const char*)&Ps[0][0] + l15*144 + l4*16);
            f16x8 pa1 = *(const f16x8*)((const char*)&Ps[0][0] + l15*144 + 64 + l4*16);
            const u16* vb = Vtg + (size_t)(dg*96 + l15)*16384 + bofs + (size_t)(t-1)*64 + l4*8;
            #pragma unroll
            for (int ni = 0; ni < 6; ++ni) {
                f16x8 va = *(const f16x8*)(vb + (size_t)ni*262144);
                f16x8 vc = *(const f16x8*)(vb + (size_t)ni*262144 + 32);
                f32x4 o = oacc[ni];
                o[0]*=fr0; o[1]*=fr1; o[2]*=fr2; o[3]*=fr3;
                o = MFMA(pa0, va, o);
                o = MFMA(pa1, vc, o);
                oacc[ni] = o;
            }
        }
        __syncthreads();                                 // B: Sp complete; Ps free
        // ---- online softmax(t): 32 threads/row (= wave half), 2 cols each
        {
            const int r = tid >> 5, c0 = (tid & 31)*2;
            const float2 v0 = *(const float2*)&Sp[0][r][c0];
            const float2 v1 = *(const float2*)&Sp[1][r][c0];
            float a0 = (v0.x + v1.x) * SM_SCALE;
            float a1 = (v0.y + v1.y) * SM_SCALE;
            const int qglob = q0 + r, kglob = t*64 + c0;
            if (kglob > qglob)     a0 = NEG_INF;
            if (kglob + 1 > qglob) a1 = NEG_INF;
            float mx = fmaxf(a0, a1);
            mx = fmaxf(mx, __shfl_xor(mx, 1));
            mx = fmaxf(mx, __shfl_xor(mx, 2));
            mx = fmaxf(mx, __shfl_xor(mx, 4));
            mx = fmaxf(mx, __shfl_xor(mx, 8));
            mx = fmaxf(mx, __shfl_xor(mx, 16));
            const float m_old = row_m[r];
            const float m_new = fmaxf(m_old, mx);        // finite for every processed tile
            const float p0 = __expf(a0 - m_new);
            const float p1 = __expf(a1 - m_new);
            float sum = p0 + p1;
            sum += __shfl_xor(sum, 1);
            sum += __shfl_xor(sum, 2);
            sum += __shfl_xor(sum, 4);
            sum += __shfl_xor(sum, 8);
            sum += __shfl_xor(sum, 16);
            const float sc = __expf(m_old - m_new);      // 0 at t=0
            if ((tid & 31) == 0) { row_m[r] = m_new; row_l[r] = row_l[r]*sc + sum; row_sc[r] = sc; }
            ushort2 pp; pp.x = f2h(p0); pp.y = f2h(p1);
            *(ushort2*)&Ps[r][c0] = pp;                  // 144B rows: 4B-aligned
        }
    }
    __syncthreads();                                     // Ps(NT-1), row_sc, row_l ready
    {                                                    // final PV(NT-1)
        const int rb = l4*4;
        const float fr0 = row_sc[rb], fr1 = row_sc[rb+1], fr2 = row_sc[rb+2], fr3 = row_sc[rb+3];
        f16x8 pa0 = *(const f16x8*)((const char*)&Ps[0][0] + l15*144 + l4*16);
        f16x8 pa1 = *(const f16x8*)((const char*)&Ps[0][0] + l15*144 + 64 + l4*16);
        const u16* vb = Vtg + (size_t)(dg*96 + l15)*16384 + bofs + (size_t)(NT-1)*64 + l4*8;
        #pragma unroll
        for (int ni = 0; ni < 6; ++ni) {
            f16x8 va = *(const f16x8*)(vb + (size_t)ni*262144);
            f16x8 vc = *(const f16x8*)(vb + (size_t)ni*262144 + 32);
            f32x4 o = oacc[ni];
            o[0]*=fr0; o[1]*=fr1; o[2]*=fr2; o[3]*=fr3;
            o = MFMA(pa0, va, o);
            o = MFMA(pa1, vc, o);
            oacc[ni] = o;
        }
    }
    {                                                    // epilogue: O /= l, store f32
        const int rb = l4*4;
        const float i0 = 1.f/row_l[rb],   i1 = 1.f/row_l[rb+1],
                    i2 = 1.f/row_l[rb+2], i3 = 1.f/row_l[rb+3];
        #pragma unroll
        for (int ni = 0; ni < 6; ++ni) {
            const size_t base = (bofs + q0 + rb) * 768 + dg*96 + ni*16 + l15;
            Og[base]        = oacc[ni][0] * i0;
            Og[base + 768]  = oacc[ni][1] * i1;
            Og[base + 1536] = oacc[ni][2] * i2;
            Og[base + 2304] = oacc[ni][3] * i3;
        }
    }
}

// ---------------------------------------------------------------- launch
extern "C" void kernel_launch(void* const* d_in, const int* in_sizes, int n_in,
                              void* d_out, int out_size, void* d_ws, size_t ws_size,
                              hipStream_t stream)
{
    const float* x  = (const float*)d_in[0];
    const float* Wq = (const float*)d_in[1];
    const float* Wk = (const float*)d_in[2];
    const float* Wv = (const float*)d_in[3];
    float* out = (float*)d_out;
    char* ws = (char*)d_ws;
    // ws layout (fp16): xb 25165824B | Wb 3538944B | Q 25165824B | K 25165824B | Vt 25165824B  (~99.4 MB)
    u16* xb = (u16*)ws;
    u16* Wb = (u16*)(ws + 25165824);
    u16* Qw = (u16*)(ws + 28704768);
    u16* Kw = (u16*)(ws + 53870592);
    u16* Vt = (u16*)(ws + 79036416);

    k_conv_x<<<12288, 256, 0, stream>>>(x, xb);
    k_conv_w<<<dim3(576, 3), 256, 0, stream>>>(Wq, Wk, Wv, Wb);
    k_gemm<<<dim3(768, 1, 3), 256, 0, stream>>>(xb, Wb, Qw, Kw, Vt);
    k_flash<<<1024, 512, 0, stream>>>(Qw, Kw, Vt, out);
}

// Round 12
// 577.065 us; speedup vs baseline: 1.5334x; 1.5334x over previous
//
#include <hip/hip_runtime.h>
#include <hip/hip_fp16.h>

typedef unsigned short u16;
typedef unsigned int   u32;
typedef __attribute__((ext_vector_type(8))) _Float16 f16x8;
typedef __attribute__((ext_vector_type(4))) float    f32x4;

#define MFMA(a,b,c) __builtin_amdgcn_mfma_f32_16x16x32_f16(a,b,c,0,0,0)

__device__ __forceinline__ u16 f2h(float f) { return __half_as_ushort(__float2half(f)); }

__device__ __forceinline__ void load_lds16(const void* g, void* l) {
    __builtin_amdgcn_global_load_lds(
        (__attribute__((address_space(1))) void*)g,
        (__attribute__((address_space(3))) void*)l,
        16, 0, 0);
}

// ---------------------------------------------------------------- converts
__global__ __launch_bounds__(256) void k_conv_x(const float* __restrict__ in, u16* __restrict__ out)
{
    int i = blockIdx.x * 256 + threadIdx.x;              // n4 = 3145728 exactly
    float4 v = ((const float4*)in)[i];
    ushort4 o; o.x = f2h(v.x); o.y = f2h(v.y); o.z = f2h(v.z); o.w = f2h(v.w);
    ((ushort4*)out)[i] = o;
}

__global__ __launch_bounds__(256) void k_conv_w(const float* __restrict__ w0, const float* __restrict__ w1,
                                                const float* __restrict__ w2, u16* __restrict__ out)
{
    const float* src = (blockIdx.y == 0) ? w0 : (blockIdx.y == 1) ? w1 : w2;
    int i = blockIdx.x * 256 + threadIdx.x;              // per-matrix n4 = 147456 exactly
    float4 v = ((const float4*)src)[i];
    ushort4 o; o.x = f2h(v.x); o.y = f2h(v.y); o.z = f2h(v.z); o.w = f2h(v.w);
    ((ushort4*)(out + (size_t)blockIdx.y * 589824))[i] = o;
}

// ---------------------------------------------------------------- QKV GEMM (C[m,n] = sum_k A[m,k]*B[n,k])
// z=0: A=x(16384x768) B=Wq -> Q[s][e]; z=1: -> K[s][e]; z=2: A=Wv(768x768) B=x -> Vt[e][s] (pre-transposed V)
__global__ __launch_bounds__(256) void k_gemm(const u16* __restrict__ xb, const u16* __restrict__ Wb,
                                              u16* __restrict__ Qw, u16* __restrict__ Kw, u16* __restrict__ Vt)
{
    __shared__ u16 As[2][128*32];
    __shared__ u16 Bs[2][128*32];
    const int tid = threadIdx.x;
    const int l = tid & 63;
    const int wr = tid >> 7, wc = (tid >> 6) & 1;        // 4 waves -> 2x2 of 64x64
    const int z = blockIdx.z, bx = blockIdx.x;
    const u16 *Ap, *Bp; u16* Cp; int m0, n0; size_t ldc;
    if (z < 2) { Ap = xb; Bp = Wb + (size_t)z*589824; Cp = (z==0)?Qw:Kw; m0=(bx/6)*128; n0=(bx%6)*128; ldc=768; }
    else       { Ap = Wb + 2*589824; Bp = xb; Cp = Vt; m0=(bx%6)*128; n0=(bx/6)*128; ldc=16384; }

    f32x4 acc[4][4];
    #pragma unroll
    for (int i=0;i<4;++i)
        #pragma unroll
        for (int j=0;j<4;++j) acc[i][j] = (f32x4){0.f,0.f,0.f,0.f};

    const int srow = tid >> 2, sg = tid & 3;
    const int wb = (tid >> 6) << 10;

    #pragma unroll
    for (int i = 0; i < 2; ++i) {                        // stage kt=0
        load_lds16(Ap + (size_t)(m0 + i*64 + srow)*768 + sg*8, (char*)&As[0][0] + i*4096 + wb);
        load_lds16(Bp + (size_t)(n0 + i*64 + srow)*768 + sg*8, (char*)&Bs[0][0] + i*4096 + wb);
    }
    __syncthreads();
    int cur = 0;
    for (int kt = 0; kt < 24; ++kt) {
        if (kt + 1 < 24) {
            const int k0 = (kt+1)*32;
            #pragma unroll
            for (int i = 0; i < 2; ++i) {
                load_lds16(Ap + (size_t)(m0 + i*64 + srow)*768 + k0 + sg*8, (char*)&As[cur^1][0] + i*4096 + wb);
                load_lds16(Bp + (size_t)(n0 + i*64 + srow)*768 + k0 + sg*8, (char*)&Bs[cur^1][0] + i*4096 + wb);
            }
        }
        f16x8 a[4], b[4];
        #pragma unroll
        for (int mi = 0; mi < 4; ++mi) a[mi] = *(const f16x8*)&As[cur][(wr*64 + mi*16 + (l&15))*32 + (l>>4)*8];
        #pragma unroll
        for (int ni = 0; ni < 4; ++ni) b[ni] = *(const f16x8*)&Bs[cur][(wc*64 + ni*16 + (l&15))*32 + (l>>4)*8];
        #pragma unroll
        for (int mi = 0; mi < 4; ++mi)
            #pragma unroll
            for (int ni = 0; ni < 4; ++ni)
                acc[mi][ni] = MFMA(a[mi], b[ni], acc[mi][ni]);
        __syncthreads();
        cur ^= 1;
    }
    const int col = l & 15, rg = (l >> 4) * 4;
    #pragma unroll
    for (int mi = 0; mi < 4; ++mi)
        #pragma unroll
        for (int ni = 0; ni < 4; ++ni)
            #pragma unroll
            for (int j = 0; j < 4; ++j)
                Cp[(size_t)(m0 + wr*64 + mi*16 + rg + j) * ldc + n0 + wc*64 + ni*16 + col] = f2h(acc[mi][ni][j]);
}

// ---------------------------------------------------------------- flash attention v12
// 512 threads / 8 waves (proven >=108 VGPR budget, round 9), QBLK=32, KVBLK=32.
// DOUBLE-BUFFERED K in LDS: stage K(t+1) issued right after barrier A(t) into
// the idle buffer -> the vmcnt drain at A(t+1) is covered by a full step
// (v9 issued under softmax only: ~11k cy/step latency wall).
// QK roles (iq2, kh4): wave = 16q x 32k x 192depth, qf[6]=24 VGPR (CORRECT
// depth coverage; v11's qf[6] with kh2 dropped half the inner product).
// kh partials plain-stored to 4 f32 Sp planes (round-4 proven numerics).
// PV roles (qg2, eg4): 16q x 192e, oacc[12]; V(t-1) 12x16B hoisted to top of
// iter (transient, L2 latency hidden under QK). Grid 512 paired (2j/255-2j).
#define SM_SCALE 0.03608439182435161f

__global__ __launch_bounds__(512) void k_flash(const u16* __restrict__ Qg, const u16* __restrict__ Kg,
                                               const u16* __restrict__ Vtg, float* __restrict__ Og)
{
    __shared__ u16 Ks[2][32*768];       // 98304 B, double-buffered, granule-swizzled ^(row&7)
    __shared__ float Sp[4][32][34];     // 17408 B, four f32 K-depth-partial planes
    __shared__ u16 Ps[2][16][40];       // 2560 B, f16 P by qg, 80B rows (16B-aligned frags)
    __shared__ float row_m[32], row_l[32], row_sc[32];   // 384 B
    // total 118,656 B -> 1 block/CU (matches measured residency anyway)

    const int tid = threadIdx.x;
    const int w = tid >> 6, l = tid & 63;
    const int l15 = l & 15, l4 = l >> 4;
    const int iq = w & 1, kh = w >> 1;                   // QK role: q-half iq, depth quarter kh
    const int qg = w & 1, eg = w >> 1;                   // PV role: 16q x 192e
    const int B = blockIdx.x;
    const int batch = B & 3, j = B >> 2;                 // j in [0,128)
    const int qi = (j < 64) ? 2*j : 255 - 2*j;           // evens first, then odds longest-first
    const int q0 = qi * 32;
    const int NT = qi + 1;                               // 32-wide KV tiles
    const size_t bofs = (size_t)batch * 4096;
    const float NEG_INF = -__builtin_inff();
    const int wbase = w << 10;

    if (tid < 32) { row_m[tid] = NEG_INF; row_l[tid] = 0.f; }

    // ---- Q slice -> registers (once): rows q0+iq*16+l15, depth kh*192 + c*32 + l4*8
    f16x8 qf[6];
    {
        const u16* qb = Qg + (bofs + q0 + iq*16 + l15)*768 + kh*192 + l4*8;
        #pragma unroll
        for (int c = 0; c < 6; ++c)
            qf[c] = *(const f16x8*)(qb + c*32);
    }
    #pragma unroll
    for (int i = 0; i < 6; ++i) {                        // stage K(0) -> Ks[0]
        int u = i*512 + tid, row = u/96, g = u - row*96, gd = g ^ (row & 7);
        load_lds16(Kg + (bofs + row)*768 + gd*8, (char*)&Ks[0][0] + i*8192 + wbase);
    }

    f32x4 oacc[12];
    #pragma unroll
    for (int i = 0; i < 12; ++i) oacc[i] = (f32x4){0.f,0.f,0.f,0.f};

    int cur = 0;
    for (int t = 0; t < NT; ++t) {
        __syncthreads();                                 // A: Ks[cur]=K(t) drained; Ps(t-1), row_sc ready; Sp free
        // ---- stage K(t+1) -> idle buffer NOW (drains at A(t+1), hidden under full step)
        if (t + 1 < NT) {
            #pragma unroll
            for (int i = 0; i < 6; ++i) {
                int u = i*512 + tid, row = u/96, g = u - row*96, gd = g ^ (row & 7);
                load_lds16(Kg + (bofs + (size_t)(t+1)*32 + row)*768 + gd*8,
                           (char*)&Ks[cur^1][0] + i*8192 + wbase);
            }
        }
        // ---- V(t-1) loads issued early (consumed in PV below)
        f16x8 vv[12];
        if (t > 0) {
            const u16* vb = Vtg + (size_t)(eg*192 + l15)*16384 + bofs + (size_t)(t-1)*32 + l4*8;
            #pragma unroll
            for (int ni = 0; ni < 12; ++ni)
                vv[ni] = *(const f16x8*)(vb + (size_t)ni*262144);
        }
        // ---- QK(t): wave (iq,kh): 16 q-rows x 32 k-cols, depth kh*192+[0,192)
        {
            const char* kbase = (const char*)&Ks[cur][0];
            const int kx = l15 & 7;
            #pragma unroll
            for (int jj = 0; jj < 2; ++jj) {             // two 16-col groups
                const char* kb = kbase + (jj*16 + l15)*1536;
                f32x4 sA = (f32x4){0.f,0.f,0.f,0.f}, sB = (f32x4){0.f,0.f,0.f,0.f};
                #pragma unroll
                for (int c = 0; c < 6; c += 2) {
                    const int ga = kh*24 + c*4 + l4, gb2 = kh*24 + (c+1)*4 + l4;
                    f16x8 ba = *(const f16x8*)(kb + (ga ^ kx)*16);
                    sA = MFMA(qf[c], ba, sA);
                    f16x8 bb = *(const f16x8*)(kb + (gb2 ^ kx)*16);
                    sB = MFMA(qf[c+1], bb, sB);
                }
                const int sr = iq*16 + l4*4, scc = jj*16 + l15;
                #pragma unroll
                for (int r = 0; r < 4; ++r)
                    Sp[kh][sr + r][scc] = sA[r] + sB[r]; // plain store: deterministic
            }
        }
        // ---- PV(t-1), lagged
        if (t > 0) {
            const int rb = l4*4;
            const float fr0 = row_sc[qg*16+rb],   fr1 = row_sc[qg*16+rb+1],
                        fr2 = row_sc[qg*16+rb+2], fr3 = row_sc[qg*16+rb+3];
            f16x8 pa = *(const f16x8*)((const char*)&Ps[qg][0][0] + l15*80 + l4*16);
            #pragma unroll
            for (int ni = 0; ni < 12; ++ni) {
                f32x4 o = oacc[ni];
                o[0]*=fr0; o[1]*=fr1; o[2]*=fr2; o[3]*=fr3;
                oacc[ni] = MFMA(pa, vv[ni], o);
            }
        }
        __syncthreads();                                 // B: Sp complete; Ps free
        // ---- online softmax(t): 16 threads/row, 2 cols each (4-plane sum, round-4 numerics)
        {
            const int r = tid >> 4, cp = tid & 15, c0 = cp*2;
            const float2 v0 = *(const float2*)&Sp[0][r][c0];
            const float2 v1 = *(const float2*)&Sp[1][r][c0];
            const float2 v2 = *(const float2*)&Sp[2][r][c0];
            const float2 v3 = *(const float2*)&Sp[3][r][c0];
            float a0 = (v0.x + v1.x + v2.x + v3.x) * SM_SCALE;
            float a1 = (v0.y + v1.y + v2.y + v3.y) * SM_SCALE;
            const int qglob = q0 + r, kglob = t*32 + c0;
            if (kglob > qglob)     a0 = NEG_INF;
            if (kglob + 1 > qglob) a1 = NEG_INF;
            float mx = fmaxf(a0, a1);
            mx = fmaxf(mx, __shfl_xor(mx, 1));
            mx = fmaxf(mx, __shfl_xor(mx, 2));
            mx = fmaxf(mx, __shfl_xor(mx, 4));
            mx = fmaxf(mx, __shfl_xor(mx, 8));
            const float m_old = row_m[r];
            const float m_new = fmaxf(m_old, mx);        // finite for every processed tile
            const float p0 = __expf(a0 - m_new);
            const float p1 = __expf(a1 - m_new);
            float sum = p0 + p1;
            sum += __shfl_xor(sum, 1);
            sum += __shfl_xor(sum, 2);
            sum += __shfl_xor(sum, 4);
            sum += __shfl_xor(sum, 8);
            const float sc = __expf(m_old - m_new);      // 0 at t=0
            if (cp == 0) { row_m[r] = m_new; row_l[r] = row_l[r]*sc + sum; row_sc[r] = sc; }
            ushort2 pp; pp.x = f2h(p0); pp.y = f2h(p1);
            *(ushort2*)&Ps[r >> 4][r & 15][c0] = pp;     // 80B rows: 4B-aligned
        }
        cur ^= 1;
    }
    __syncthreads();                                     // Ps(NT-1), row_sc, row_l ready
    {                                                    // final PV(NT-1)
        const int rb = l4*4;
        const float fr0 = row_sc[qg*16+rb],   fr1 = row_sc[qg*16+rb+1],
                    fr2 = row_sc[qg*16+rb+2], fr3 = row_sc[qg*16+rb+3];
        f16x8 pa = *(const f16x8*)((const char*)&Ps[qg][0][0] + l15*80 + l4*16);
        const u16* vb = Vtg + (size_t)(eg*192 + l15)*16384 + bofs + (size_t)(NT-1)*32 + l4*8;
        #pragma unroll
        for (int ni = 0; ni < 12; ++ni) {
            f16x8 vv = *(const f16x8*)(vb + (size_t)ni*262144);
            f32x4 o = oacc[ni];
            o[0]*=fr0; o[1]*=fr1; o[2]*=fr2; o[3]*=fr3;
            oacc[ni] = MFMA(pa, vv, o);
        }
    }
    {                                                    // epilogue: O /= l, store f32
        const int rb = l4*4;
        const float i0 = 1.f/row_l[qg*16+rb],   i1 = 1.f/row_l[qg*16+rb+1],
                    i2 = 1.f/row_l[qg*16+rb+2], i3 = 1.f/row_l[qg*16+rb+3];
        #pragma unroll
        for (int ni = 0; ni < 12; ++ni) {
            const size_t base = (bofs + q0 + qg*16 + rb) * 768 + eg*192 + ni*16 + l15;
            Og[base]        = oacc[ni][0] * i0;
            Og[base + 768]  = oacc[ni][1] * i1;
            Og[base + 1536] = oacc[ni][2] * i2;
            Og[base + 2304] = oacc[ni][3] * i3;
        }
    }
}

// ---------------------------------------------------------------- launch
extern "C" void kernel_launch(void* const* d_in, const int* in_sizes, int n_in,
                              void* d_out, int out_size, void* d_ws, size_t ws_size,
                              hipStream_t stream)
{
    const float* x  = (const float*)d_in[0];
    const float* Wq = (const float*)d_in[1];
    const float* Wk = (const float*)d_in[2];
    const float* Wv = (const float*)d_in[3];
    float* out = (float*)d_out;
    char* ws = (char*)d_ws;
    // ws layout (fp16): xb 25165824B | Wb 3538944B | Q 25165824B | K 25165824B | Vt 25165824B  (~99.4 MB)
    u16* xb = (u16*)ws;
    u16* Wb = (u16*)(ws + 25165824);
    u16* Qw = (u16*)(ws + 28704768);
    u16* Kw = (u16*)(ws + 53870592);
    u16* Vt = (u16*)(ws + 79036416);

    k_conv_x<<<12288, 256, 0, stream>>>(x, xb);
    k_conv_w<<<dim3(576, 3), 256, 0, stream>>>(Wq, Wk, Wv, Wb);
    k_gemm<<<dim3(768, 1, 3), 256, 0, stream>>>(xb, Wb, Qw, Kw, Vt);
    k_flash<<<512, 512, 0, stream>>>(Qw, Kw, Vt, out);
}